// Round 1
// baseline (2111.538 us; speedup 1.0000x reference)
//
#include <hip/hip_runtime.h>
#include <hip/hip_bf16.h>

// Problem constants (match reference setup_inputs)
#define NN 50000
#define EE 800000
#define F_IN 128
#define HID 32
#define H1 4
#define H2 8
#define E_DEC 100000
#define NEG_SLOPE 0.2f

// ---------------- fill zeros ----------------
__global__ void fill0_k(float4* __restrict__ p, int n4) {
    int i = blockIdx.x * blockDim.x + threadIdx.x;
    if (i < n4) p[i] = make_float4(0.f, 0.f, 0.f, 0.f);
}

// ---------------- GEMM + attention-logit terms ----------------
// One row per block; blockDim = OUT. Computes h = x @ W (row), and
// al_s[n,hd] = sum_c h[n,hd*32+c]*a_src[hd,c], al_d likewise.
template <int OUT, int H>
__global__ void gemm_al_k(const float* __restrict__ X, const float* __restrict__ W,
                          const float* __restrict__ a_src, const float* __restrict__ a_dst,
                          float* __restrict__ Hout, float* __restrict__ als,
                          float* __restrict__ ald) {
    __shared__ float xs[128];
    const int row = blockIdx.x;
    const int t = threadIdx.x;
    if (t < 128) xs[t] = X[(long long)row * 128 + t];
    __syncthreads();
    float acc = 0.f;
    const float* wc = W + t;
#pragma unroll 8
    for (int k = 0; k < 128; ++k) acc += xs[k] * wc[(long long)k * OUT];
    Hout[(long long)row * OUT + t] = acc;
    const int hd = t >> 5, c = t & 31;
    float ps = acc * a_src[hd * 32 + c];
    float pd = acc * a_dst[hd * 32 + c];
#pragma unroll
    for (int m = 16; m >= 1; m >>= 1) {
        ps += __shfl_xor(ps, m, 32);
        pd += __shfl_xor(pd, m, 32);
    }
    if (c == 0) {
        als[row * H + hd] = ps;
        ald[row * H + hd] = pd;
    }
}

// ---------------- softmax denominator (segment sum of exp) ----------------
template <int H>
__global__ void denom_k(const int* __restrict__ ei, const float* __restrict__ als,
                        const float* __restrict__ ald, float* __restrict__ denom) {
    const int e = blockIdx.x * blockDim.x + threadIdx.x;
    const int ET = EE + NN;
    if (e >= ET) return;
    int s, d;
    if (e < EE) { s = ei[e]; d = ei[EE + e]; } else { s = d = e - EE; }
#pragma unroll
    for (int hd = 0; hd < H; ++hd) {
        float lg = als[s * H + hd] + ald[d * H + hd];
        lg = lg > 0.f ? lg : NEG_SLOPE * lg;
        atomicAdd(&denom[d * H + hd], __expf(lg));
    }
}

// ---------------- message aggregation (segment sum of alpha * h[src]) ----------------
template <int H>
__global__ void agg_k(const int* __restrict__ ei, const float* __restrict__ als,
                      const float* __restrict__ ald, const float* __restrict__ denom,
                      const float* __restrict__ Hin, float* __restrict__ out) {
    const int OUT = H * 32;
    const int SHIFT = (H == 4) ? 7 : 8;
    const int gid = blockIdx.x * blockDim.x + threadIdx.x;
    const int tot = (EE + NN) * OUT;
    if (gid >= tot) return;
    const int c = gid & (OUT - 1);
    const int e = gid >> SHIFT;
    int s, d;
    if (e < EE) { s = ei[e]; d = ei[EE + e]; } else { s = d = e - EE; }
    const int hd = c >> 5;
    float lg = als[s * H + hd] + ald[d * H + hd];
    lg = lg > 0.f ? lg : NEG_SLOPE * lg;
    const float alpha = __expf(lg) / (denom[d * H + hd] + 1e-16f);
    atomicAdd(&out[(long long)d * OUT + c], Hin[(long long)s * OUT + c] * alpha);
}

// ---------------- bias (+ optional relu), in place ----------------
template <int OUT, bool RELU>
__global__ void bias_k(float* __restrict__ z, const float* __restrict__ b) {
    const int i = blockIdx.x * blockDim.x + threadIdx.x;
    if (i >= NN * OUT) return;
    float v = z[i] + b[i & (OUT - 1)];
    if (RELU) v = v > 0.f ? v : 0.f;
    z[i] = v;
}

// ---------------- decode: logits = sum(z2[a]*z2[b]) ----------------
__global__ void decode_k(const int* __restrict__ pei, const int* __restrict__ nei,
                         const float* __restrict__ z2, float* __restrict__ out) {
    const int w = threadIdx.x >> 6, lane = threadIdx.x & 63;
    const int idx = blockIdx.x * 4 + w;
    if (idx >= 2 * E_DEC) return;
    int a, b;
    if (idx < E_DEC) {
        a = pei[idx];
        b = pei[E_DEC + idx];
    } else {
        const int j = idx - E_DEC;
        a = nei[j];
        b = nei[E_DEC + j];
    }
    const float* za = z2 + (long long)a * 256;
    const float* zb = z2 + (long long)b * 256;
    float s = 0.f;
#pragma unroll
    for (int r = 0; r < 4; ++r) s += za[lane + 64 * r] * zb[lane + 64 * r];
#pragma unroll
    for (int m = 32; m >= 1; m >>= 1) s += __shfl_xor(s, m, 64);
    if (lane == 0) out[idx] = s;
}

extern "C" void kernel_launch(void* const* d_in, const int* in_sizes, int n_in,
                              void* d_out, int out_size, void* d_ws, size_t ws_size,
                              hipStream_t stream) {
    const float* x = (const float*)d_in[0];
    const int* ei = (const int*)d_in[1];
    const int* pei = (const int*)d_in[2];
    const int* nei = (const int*)d_in[3];
    const float* W1 = (const float*)d_in[4];
    const float* as1 = (const float*)d_in[5];
    const float* ad1 = (const float*)d_in[6];
    const float* b1 = (const float*)d_in[7];
    const float* W2 = (const float*)d_in[8];
    const float* as2 = (const float*)d_in[9];
    const float* ad2 = (const float*)d_in[10];
    const float* b2 = (const float*)d_in[11];
    float* out = (float*)d_out;

    // Workspace layout (floats). First block must be zeroed each call.
    float* ws = (float*)d_ws;
    float* denom1 = ws;                         // NN*H1        = 200000
    float* agg1 = denom1 + NN * H1;             // NN*128       = 6.4M (becomes z1)
    float* denom2 = agg1 + (long long)NN * 128; // NN*H2        = 400000
    float* agg2 = denom2 + NN * H2;             // NN*256       = 12.8M (becomes z2)
    float* h1 = agg2 + (long long)NN * 256;     // NN*128
    float* als1 = h1 + (long long)NN * 128;     // NN*H1
    float* ald1 = als1 + NN * H1;               // NN*H1
    float* h2 = ald1 + NN * H1;                 // NN*256
    float* als2 = h2 + (long long)NN * 256;     // NN*H2
    float* ald2 = als2 + NN * H2;               // NN*H2

    const int ET = EE + NN;
    const int zero_floats = NN * H1 + NN * 128 + NN * H2 + NN * 256;  // contiguous
    const int n4 = zero_floats / 4;
    fill0_k<<<(n4 + 255) / 256, 256, 0, stream>>>((float4*)ws, n4);

    // ---- conv1 ----
    gemm_al_k<128, H1><<<NN, 128, 0, stream>>>(x, W1, as1, ad1, h1, als1, ald1);
    denom_k<H1><<<(ET + 255) / 256, 256, 0, stream>>>(ei, als1, ald1, denom1);
    {
        const int tot = ET * 128;
        agg_k<H1><<<(tot + 255) / 256, 256, 0, stream>>>(ei, als1, ald1, denom1, h1, agg1);
    }
    bias_k<128, true><<<(NN * 128 + 255) / 256, 256, 0, stream>>>(agg1, b1);

    // ---- conv2 ----
    gemm_al_k<256, H2><<<NN, 256, 0, stream>>>(agg1, W2, as2, ad2, h2, als2, ald2);
    denom_k<H2><<<(ET + 255) / 256, 256, 0, stream>>>(ei, als2, ald2, denom2);
    {
        const int tot = ET * 256;
        agg_k<H2><<<(tot + 255) / 256, 256, 0, stream>>>(ei, als2, ald2, denom2, h2, agg2);
    }
    bias_k<256, false><<<(NN * 256 + 255) / 256, 256, 0, stream>>>(agg2, b2);

    // ---- decode ----
    decode_k<<<(2 * E_DEC + 3) / 4, 256, 0, stream>>>(pei, nei, agg2, out);
}

// Round 2
// 684.957 us; speedup vs baseline: 3.0827x; 3.0827x over previous
//
#include <hip/hip_runtime.h>
#include <hip/hip_bf16.h>

#define NN 50000
#define EE 800000
#define ET (EE + NN)
#define F_IN 128
#define HID 32
#define H1 4
#define H2 8
#define E_DEC 100000
#define NEG_SLOPE 0.2f

// ---------------- zero ints ----------------
__global__ void fillint_k(int* __restrict__ p, int n) {
    int i = blockIdx.x * blockDim.x + threadIdx.x;
    if (i < n) p[i] = 0;
}

// ---------------- CSR build: histogram of dst ----------------
__global__ void hist_k(const int* __restrict__ ei, int* __restrict__ counts) {
    int e = blockIdx.x * blockDim.x + threadIdx.x;
    if (e >= ET) return;
    int d = (e < EE) ? ei[EE + e] : e - EE;
    atomicAdd(&counts[d], 1);
}

// ---------------- hierarchical exclusive scan over counts[NN] ----------------
__global__ void scan1_k(const int* __restrict__ counts, int* __restrict__ bsum) {
    __shared__ int sh[256];
    int t = threadIdx.x;
    int i = blockIdx.x * 256 + t;
    sh[t] = (i < NN) ? counts[i] : 0;
    __syncthreads();
    for (int off = 128; off > 0; off >>= 1) {
        if (t < off) sh[t] += sh[t + off];
        __syncthreads();
    }
    if (t == 0) bsum[blockIdx.x] = sh[0];
}

__global__ void scan2_k(int* __restrict__ bsum, int nb, int* __restrict__ start) {
    __shared__ int sh[256];
    int t = threadIdx.x;
    int v = (t < nb) ? bsum[t] : 0;
    sh[t] = v;
    __syncthreads();
    for (int off = 1; off < 256; off <<= 1) {
        int u = (t >= off) ? sh[t - off] : 0;
        __syncthreads();
        sh[t] += u;
        __syncthreads();
    }
    if (t < nb) bsum[t] = sh[t] - v;  // exclusive block offsets
    if (t == 0) start[NN] = ET;
}

__global__ void scan3_k(const int* __restrict__ counts, const int* __restrict__ bsum,
                        int* __restrict__ start, int* __restrict__ cursor) {
    __shared__ int sh[256];
    int t = threadIdx.x;
    int i = blockIdx.x * 256 + t;
    int c = (i < NN) ? counts[i] : 0;
    sh[t] = c;
    __syncthreads();
    for (int off = 1; off < 256; off <<= 1) {
        int u = (t >= off) ? sh[t - off] : 0;
        __syncthreads();
        sh[t] += u;
        __syncthreads();
    }
    int excl = sh[t] - c + bsum[blockIdx.x];
    if (i < NN) {
        start[i] = excl;
        cursor[i] = excl;
    }
}

__global__ void scatter_k(const int* __restrict__ ei, int* __restrict__ cursor,
                          int* __restrict__ csr) {
    int e = blockIdx.x * blockDim.x + threadIdx.x;
    if (e >= ET) return;
    int s, d;
    if (e < EE) { s = ei[e]; d = ei[EE + e]; } else { s = d = e - EE; }
    int slot = atomicAdd(&cursor[d], 1);
    csr[slot] = s;
}

// ---------------- GEMM (TM rows/block) + fused attention-logit terms ----------------
// h = X @ W ; als[n,hd] = sum_c h[n,hd,c]*a_src[hd,c] ; ald likewise.
template <int OUT, int H, int TM>
__global__ void gemm_al_k(const float* __restrict__ X, const float* __restrict__ W,
                          const float* __restrict__ a_src, const float* __restrict__ a_dst,
                          float* __restrict__ Hout, float* __restrict__ als,
                          float* __restrict__ ald) {
    __shared__ float xs[TM][128];
    const int r0 = blockIdx.x * TM;
    const int t = threadIdx.x;  // 0..OUT-1, owns output column t
    for (int i = t; i < TM * 128; i += OUT) {
        xs[i >> 7][i & 127] = X[(long long)(r0 + (i >> 7)) * 128 + (i & 127)];
    }
    __syncthreads();
    float acc[TM];
#pragma unroll
    for (int r = 0; r < TM; ++r) acc[r] = 0.f;
    for (int k = 0; k < 128; k += 4) {
        const float w0 = W[(k + 0) * OUT + t];
        const float w1 = W[(k + 1) * OUT + t];
        const float w2 = W[(k + 2) * OUT + t];
        const float w3 = W[(k + 3) * OUT + t];
#pragma unroll
        for (int r = 0; r < TM; ++r) {
            const float4 xv = *(const float4*)&xs[r][k];
            acc[r] += xv.x * w0 + xv.y * w1 + xv.z * w2 + xv.w * w3;
        }
    }
    const int hd = t >> 5, c = t & 31;
    const float asc = a_src[hd * 32 + c];
    const float adc = a_dst[hd * 32 + c];
#pragma unroll
    for (int r = 0; r < TM; ++r) {
        Hout[(long long)(r0 + r) * OUT + t] = acc[r];
        float ps = acc[r] * asc;
        float pd = acc[r] * adc;
#pragma unroll
        for (int m = 16; m >= 1; m >>= 1) {
            ps += __shfl_xor(ps, m, 32);
            pd += __shfl_xor(pd, m, 32);
        }
        if (c == 0) {
            als[(r0 + r) * H + hd] = ps;
            ald[(r0 + r) * H + hd] = pd;
        }
    }
}

// ---------------- CSR gather: softmax-weighted aggregation + bias (+relu) ----------------
template <int OUT, int H, bool RELU>
__global__ void gather_k(const int* __restrict__ start, const int* __restrict__ csr,
                         const float* __restrict__ als, const float* __restrict__ ald,
                         const float* __restrict__ Hin, const float* __restrict__ bias,
                         float* __restrict__ out) {
    const int d = blockIdx.x;
    const int t = threadIdx.x;  // channel
    const int hd = t >> 5;
    const int beg = start[d];
    const int end = start[d + 1];
    const float aldd = ald[d * H + hd];
    float acc = 0.f, den = 0.f;
    for (int i = beg; i < end; ++i) {
        const int s = csr[i];
        float lg = als[s * H + hd] + aldd;
        lg = lg > 0.f ? lg : NEG_SLOPE * lg;
        const float w = __expf(lg);
        den += w;
        acc += w * Hin[(long long)s * OUT + t];
    }
    float v = acc / (den + 1e-16f) + bias[t];
    if (RELU) v = v > 0.f ? v : 0.f;
    out[(long long)d * OUT + t] = v;
}

// ---------------- decode ----------------
__global__ void decode_k(const int* __restrict__ pei, const int* __restrict__ nei,
                         const float* __restrict__ z2, float* __restrict__ out) {
    const int w = threadIdx.x >> 6, lane = threadIdx.x & 63;
    const int idx = blockIdx.x * 4 + w;
    if (idx >= 2 * E_DEC) return;
    int a, b;
    if (idx < E_DEC) {
        a = pei[idx];
        b = pei[E_DEC + idx];
    } else {
        const int j = idx - E_DEC;
        a = nei[j];
        b = nei[E_DEC + j];
    }
    const float* za = z2 + (long long)a * 256;
    const float* zb = z2 + (long long)b * 256;
    float s = 0.f;
#pragma unroll
    for (int r = 0; r < 4; ++r) s += za[lane + 64 * r] * zb[lane + 64 * r];
#pragma unroll
    for (int m = 32; m >= 1; m >>= 1) s += __shfl_xor(s, m, 64);
    if (lane == 0) out[idx] = s;
}

extern "C" void kernel_launch(void* const* d_in, const int* in_sizes, int n_in,
                              void* d_out, int out_size, void* d_ws, size_t ws_size,
                              hipStream_t stream) {
    const float* x = (const float*)d_in[0];
    const int* ei = (const int*)d_in[1];
    const int* pei = (const int*)d_in[2];
    const int* nei = (const int*)d_in[3];
    const float* W1 = (const float*)d_in[4];
    const float* as1 = (const float*)d_in[5];
    const float* ad1 = (const float*)d_in[6];
    const float* b1 = (const float*)d_in[7];
    const float* W2 = (const float*)d_in[8];
    const float* as2 = (const float*)d_in[9];
    const float* ad2 = (const float*)d_in[10];
    const float* b2 = (const float*)d_in[11];
    float* out = (float*)d_out;

    // ---- workspace layout ----
    int* counts = (int*)d_ws;              // NN
    int* start = counts + NN;              // NN+1
    int* cursor = start + NN + 1;          // NN
    int* bsum = cursor + NN;               // 256
    int* csr = bsum + 256;                 // ET
    float* fbase = (float*)(csr + ET);
    float* buf1 = fbase;                        // 12.8M floats: h1 | z1, later reused as z2
    float* h1 = buf1;                           // NN*128
    float* z1 = buf1 + (long long)NN * 128;     // NN*128
    float* z2 = buf1;                           // NN*256 (aliases h1+z1, both dead by then)
    float* h2 = buf1 + (long long)NN * 256;     // NN*256
    float* als1 = h2 + (long long)NN * 256;     // NN*H1
    float* ald1 = als1 + NN * H1;
    float* als2 = ald1 + NN * H1;               // NN*H2
    float* ald2 = als2 + NN * H2;

    const int NB = (NN + 255) / 256;  // 196

    // ---- CSR build ----
    fillint_k<<<NB, 256, 0, stream>>>(counts, NN);
    hist_k<<<(ET + 255) / 256, 256, 0, stream>>>(ei, counts);
    scan1_k<<<NB, 256, 0, stream>>>(counts, bsum);
    scan2_k<<<1, 256, 0, stream>>>(bsum, NB, start);
    scan3_k<<<NB, 256, 0, stream>>>(counts, bsum, start, cursor);
    scatter_k<<<(ET + 255) / 256, 256, 0, stream>>>(ei, cursor, csr);

    // ---- conv1 ----
    gemm_al_k<128, H1, 8><<<NN / 8, 128, 0, stream>>>(x, W1, as1, ad1, h1, als1, ald1);
    gather_k<128, H1, true><<<NN, 128, 0, stream>>>(start, csr, als1, ald1, h1, b1, z1);

    // ---- conv2 ----
    gemm_al_k<256, H2, 8><<<NN / 8, 256, 0, stream>>>(z1, W2, as2, ad2, h2, als2, ald2);
    gather_k<256, H2, false><<<NN, 256, 0, stream>>>(start, csr, als2, ald2, h2, b2, z2);

    // ---- decode ----
    decode_k<<<(2 * E_DEC + 3) / 4, 256, 0, stream>>>(pei, nei, z2, out);
}

// Round 4
// 487.084 us; speedup vs baseline: 4.3351x; 1.4062x over previous
//
#include <hip/hip_runtime.h>
#include <hip/hip_bf16.h>

#define NN 50000
#define EE 800000
#define ET (EE + NN)
#define F_IN 128
#define HID 32
#define H1 4
#define H2 8
#define E_DEC 100000
#define NEG_SLOPE 0.2f

__device__ __forceinline__ __hip_bfloat162 pack_bf162(float vx, float vy) {
    __hip_bfloat162 o;
    o.x = __float2bfloat16(vx);
    o.y = __float2bfloat16(vy);
    return o;
}

// ---------------- zero ints ----------------
__global__ void fillint_k(int* __restrict__ p, int n) {
    int i = blockIdx.x * blockDim.x + threadIdx.x;
    if (i < n) p[i] = 0;
}

// ---------------- CSR build: histogram of dst ----------------
__global__ void hist_k(const int* __restrict__ ei, int* __restrict__ counts) {
    int e = blockIdx.x * blockDim.x + threadIdx.x;
    if (e >= ET) return;
    int d = (e < EE) ? ei[EE + e] : e - EE;
    atomicAdd(&counts[d], 1);
}

// ---------------- hierarchical exclusive scan over counts[NN] ----------------
__global__ void scan1_k(const int* __restrict__ counts, int* __restrict__ bsum) {
    __shared__ int sh[256];
    int t = threadIdx.x;
    int i = blockIdx.x * 256 + t;
    sh[t] = (i < NN) ? counts[i] : 0;
    __syncthreads();
    for (int off = 128; off > 0; off >>= 1) {
        if (t < off) sh[t] += sh[t + off];
        __syncthreads();
    }
    if (t == 0) bsum[blockIdx.x] = sh[0];
}

__global__ void scan2_k(int* __restrict__ bsum, int nb, int* __restrict__ start) {
    __shared__ int sh[256];
    int t = threadIdx.x;
    int v = (t < nb) ? bsum[t] : 0;
    sh[t] = v;
    __syncthreads();
    for (int off = 1; off < 256; off <<= 1) {
        int u = (t >= off) ? sh[t - off] : 0;
        __syncthreads();
        sh[t] += u;
        __syncthreads();
    }
    if (t < nb) bsum[t] = sh[t] - v;  // exclusive block offsets
    if (t == 0) start[NN] = ET;
}

__global__ void scan3_k(const int* __restrict__ counts, const int* __restrict__ bsum,
                        int* __restrict__ start, int* __restrict__ cursor) {
    __shared__ int sh[256];
    int t = threadIdx.x;
    int i = blockIdx.x * 256 + t;
    int c = (i < NN) ? counts[i] : 0;
    sh[t] = c;
    __syncthreads();
    for (int off = 1; off < 256; off <<= 1) {
        int u = (t >= off) ? sh[t - off] : 0;
        __syncthreads();
        sh[t] += u;
        __syncthreads();
    }
    int excl = sh[t] - c + bsum[blockIdx.x];
    if (i < NN) {
        start[i] = excl;
        cursor[i] = excl;
    }
}

__global__ void scatter_k(const int* __restrict__ ei, int* __restrict__ cursor,
                          int* __restrict__ csr) {
    int e = blockIdx.x * blockDim.x + threadIdx.x;
    if (e >= ET) return;
    int s, d;
    if (e < EE) { s = ei[e]; d = ei[EE + e]; } else { s = d = e - EE; }
    int slot = atomicAdd(&cursor[d], 1);
    csr[slot] = s;
}

// ---------------- GEMM (TM rows/block) + fused attention-logit terms ----------------
// h = X @ W (stored bf16); als[n,hd] = sum_c h[n,hd,c]*a_src[hd,c]; ald likewise.
template <int OUT, int H, int TM>
__global__ void gemm_al_k(const float* __restrict__ X, const float* __restrict__ W,
                          const float* __restrict__ a_src, const float* __restrict__ a_dst,
                          __hip_bfloat16* __restrict__ Hout, float* __restrict__ als,
                          float* __restrict__ ald) {
    __shared__ float xs[TM][128];
    const int r0 = blockIdx.x * TM;
    const int t = threadIdx.x;  // 0..OUT-1, owns output column t
    for (int i = t; i < TM * 128; i += OUT) {
        xs[i >> 7][i & 127] = X[(long long)(r0 + (i >> 7)) * 128 + (i & 127)];
    }
    __syncthreads();
    float acc[TM];
#pragma unroll
    for (int r = 0; r < TM; ++r) acc[r] = 0.f;
    for (int k = 0; k < 128; k += 4) {
        const float w0 = W[(k + 0) * OUT + t];
        const float w1 = W[(k + 1) * OUT + t];
        const float w2 = W[(k + 2) * OUT + t];
        const float w3 = W[(k + 3) * OUT + t];
#pragma unroll
        for (int r = 0; r < TM; ++r) {
            const float4 xv = *(const float4*)&xs[r][k];
            acc[r] += xv.x * w0 + xv.y * w1 + xv.z * w2 + xv.w * w3;
        }
    }
    const int hd = t >> 5, c = t & 31;
    const float asc = a_src[hd * 32 + c];
    const float adc = a_dst[hd * 32 + c];
#pragma unroll
    for (int r = 0; r < TM; ++r) {
        Hout[(long long)(r0 + r) * OUT + t] = __float2bfloat16(acc[r]);
        float ps = acc[r] * asc;
        float pd = acc[r] * adc;
#pragma unroll
        for (int m = 16; m >= 1; m >>= 1) {
            ps += __shfl_xor(ps, m, 32);
            pd += __shfl_xor(pd, m, 32);
        }
        if (c == 0) {
            als[(r0 + r) * H + hd] = ps;
            ald[(r0 + r) * H + hd] = pd;
        }
    }
}

// ---------------- CSR gather: softmax-weighted aggregation + bias (+relu) ----------------
// Block = dst node; OUT/2 threads, each owns 2 channels (bf162). Unroll 4 edges for MLP.
template <int OUT, int H, bool RELU, bool OUT_BF16>
__global__ void gather_k(const int* __restrict__ start, const int* __restrict__ csr,
                         const float* __restrict__ als, const float* __restrict__ ald,
                         const __hip_bfloat162* __restrict__ Hin,
                         const float* __restrict__ bias, void* __restrict__ outp) {
    const int d = blockIdx.x;
    const int t = threadIdx.x;      // owns channels 2t, 2t+1
    const int hd = t >> 4;          // (2t) >> 5
    const int beg = start[d];
    const int end = start[d + 1];
    const float aldd = ald[d * H + hd];
    float accx = 0.f, accy = 0.f, den = 0.f;
    int i = beg;
    for (; i + 4 <= end; i += 4) {
        const int s0 = csr[i], s1 = csr[i + 1], s2 = csr[i + 2], s3 = csr[i + 3];
        float l0 = als[s0 * H + hd] + aldd;
        float l1 = als[s1 * H + hd] + aldd;
        float l2 = als[s2 * H + hd] + aldd;
        float l3 = als[s3 * H + hd] + aldd;
        const __hip_bfloat162 g0 = Hin[(long long)s0 * (OUT / 2) + t];
        const __hip_bfloat162 g1 = Hin[(long long)s1 * (OUT / 2) + t];
        const __hip_bfloat162 g2 = Hin[(long long)s2 * (OUT / 2) + t];
        const __hip_bfloat162 g3 = Hin[(long long)s3 * (OUT / 2) + t];
        l0 = l0 > 0.f ? l0 : NEG_SLOPE * l0;
        l1 = l1 > 0.f ? l1 : NEG_SLOPE * l1;
        l2 = l2 > 0.f ? l2 : NEG_SLOPE * l2;
        l3 = l3 > 0.f ? l3 : NEG_SLOPE * l3;
        const float w0 = __expf(l0), w1 = __expf(l1), w2 = __expf(l2), w3 = __expf(l3);
        den += (w0 + w1) + (w2 + w3);
        const float2 f0 = __bfloat1622float2(g0);
        const float2 f1 = __bfloat1622float2(g1);
        const float2 f2 = __bfloat1622float2(g2);
        const float2 f3 = __bfloat1622float2(g3);
        accx += w0 * f0.x + w1 * f1.x + w2 * f2.x + w3 * f3.x;
        accy += w0 * f0.y + w1 * f1.y + w2 * f2.y + w3 * f3.y;
    }
    for (; i < end; ++i) {
        const int s = csr[i];
        float lg = als[s * H + hd] + aldd;
        lg = lg > 0.f ? lg : NEG_SLOPE * lg;
        const float w = __expf(lg);
        const float2 f = __bfloat1622float2(Hin[(long long)s * (OUT / 2) + t]);
        den += w;
        accx += w * f.x;
        accy += w * f.y;
    }
    const float inv = 1.f / (den + 1e-16f);
    float vx = accx * inv + bias[2 * t];
    float vy = accy * inv + bias[2 * t + 1];
    if (RELU) {
        vx = vx > 0.f ? vx : 0.f;
        vy = vy > 0.f ? vy : 0.f;
    }
    if (OUT_BF16) {
        ((__hip_bfloat162*)outp)[(long long)d * (OUT / 2) + t] = pack_bf162(vx, vy);
    } else {
        ((float2*)outp)[(long long)d * (OUT / 2) + t] = make_float2(vx, vy);
    }
}

// ---------------- decode: logits = sum(z2[a]*z2[b]), z2 in bf16 ----------------
__global__ void decode_k(const int* __restrict__ pei, const int* __restrict__ nei,
                         const __hip_bfloat162* __restrict__ z2, float* __restrict__ out) {
    const int w = threadIdx.x >> 6, lane = threadIdx.x & 63;
    const int idx = blockIdx.x * 4 + w;
    if (idx >= 2 * E_DEC) return;
    int a, b;
    if (idx < E_DEC) {
        a = pei[idx];
        b = pei[E_DEC + idx];
    } else {
        const int j = idx - E_DEC;
        a = nei[j];
        b = nei[E_DEC + j];
    }
    const __hip_bfloat162* za = z2 + (long long)a * 128;
    const __hip_bfloat162* zb = z2 + (long long)b * 128;
    float s = 0.f;
#pragma unroll
    for (int r = 0; r < 2; ++r) {
        const float2 fa = __bfloat1622float2(za[lane + 64 * r]);
        const float2 fb = __bfloat1622float2(zb[lane + 64 * r]);
        s += fa.x * fb.x + fa.y * fb.y;
    }
#pragma unroll
    for (int m = 32; m >= 1; m >>= 1) s += __shfl_xor(s, m, 64);
    if (lane == 0) out[idx] = s;
}

extern "C" void kernel_launch(void* const* d_in, const int* in_sizes, int n_in,
                              void* d_out, int out_size, void* d_ws, size_t ws_size,
                              hipStream_t stream) {
    const float* x = (const float*)d_in[0];
    const int* ei = (const int*)d_in[1];
    const int* pei = (const int*)d_in[2];
    const int* nei = (const int*)d_in[3];
    const float* W1 = (const float*)d_in[4];
    const float* as1 = (const float*)d_in[5];
    const float* ad1 = (const float*)d_in[6];
    const float* b1 = (const float*)d_in[7];
    const float* W2 = (const float*)d_in[8];
    const float* as2 = (const float*)d_in[9];
    const float* ad2 = (const float*)d_in[10];
    const float* b2 = (const float*)d_in[11];
    float* out = (float*)d_out;

    // ---- workspace layout ----
    int* counts = (int*)d_ws;              // NN
    int* start = counts + NN;              // NN+1
    int* cursor = start + NN + 1;          // NN
    int* bsum = cursor + NN;               // 256
    int* csr = bsum + 256;                 // ET
    // bf16 region
    __hip_bfloat16* h1 = (__hip_bfloat16*)(csr + ET);            // NN*128 bf16
    __hip_bfloat16* h2 = h1 + (long long)NN * 128;               // NN*256 bf16
    __hip_bfloat16* z2 = h2 + (long long)NN * 256;               // NN*256 bf16
    // fp32 region
    float* z1 = (float*)(z2 + (long long)NN * 256);              // NN*128 f32
    float* als1 = z1 + (long long)NN * 128;                      // NN*H1
    float* ald1 = als1 + NN * H1;
    float* als2 = ald1 + NN * H1;                                // NN*H2
    float* ald2 = als2 + NN * H2;

    const int NB = (NN + 255) / 256;  // 196

    // ---- CSR build ----
    fillint_k<<<NB, 256, 0, stream>>>(counts, NN);
    hist_k<<<(ET + 255) / 256, 256, 0, stream>>>(ei, counts);
    scan1_k<<<NB, 256, 0, stream>>>(counts, bsum);
    scan2_k<<<1, 256, 0, stream>>>(bsum, NB, start);
    scan3_k<<<NB, 256, 0, stream>>>(counts, bsum, start, cursor);
    scatter_k<<<(ET + 255) / 256, 256, 0, stream>>>(ei, cursor, csr);

    // ---- conv1 ----
    gemm_al_k<128, H1, 8><<<NN / 8, 128, 0, stream>>>(x, W1, as1, ad1, h1, als1, ald1);
    gather_k<128, H1, true, false><<<NN, 64, 0, stream>>>(
        start, csr, als1, ald1, (const __hip_bfloat162*)h1, b1, z1);

    // ---- conv2 ----
    gemm_al_k<256, H2, 8><<<NN / 8, 256, 0, stream>>>(z1, W2, as2, ad2, h2, als2, ald2);
    gather_k<256, H2, false, true><<<NN, 128, 0, stream>>>(
        start, csr, als2, ald2, (const __hip_bfloat162*)h2, b2, z2);

    // ---- decode ----
    decode_k<<<(2 * E_DEC + 3) / 4, 256, 0, stream>>>(
        pei, nei, (const __hip_bfloat162*)z2, out);
}

// Round 5
// 382.166 us; speedup vs baseline: 5.5252x; 1.2745x over previous
//
#include <hip/hip_runtime.h>
#include <hip/hip_bf16.h>

#define NN 50000
#define EE 800000
#define ET (EE + NN)
#define F_IN 128
#define HID 32
#define H1 4
#define H2 8
#define E_DEC 100000
#define NEG_SLOPE 0.2f

typedef __attribute__((ext_vector_type(8))) short short8;
typedef __attribute__((ext_vector_type(4))) float floatx4;

__device__ __forceinline__ unsigned short f2b(float f) {
    __hip_bfloat16 h = __float2bfloat16(f);
    return *reinterpret_cast<unsigned short*>(&h);
}
__device__ __forceinline__ float b2f(unsigned short u) {
    return __uint_as_float(((unsigned int)u) << 16);
}
__device__ __forceinline__ __hip_bfloat162 pack_bf162(float vx, float vy) {
    __hip_bfloat162 o;
    o.x = __float2bfloat16(vx);
    o.y = __float2bfloat16(vy);
    return o;
}

// ---------------- zero ints ----------------
__global__ void fillint_k(int* __restrict__ p, int n) {
    int i = blockIdx.x * blockDim.x + threadIdx.x;
    if (i < n) p[i] = 0;
}

// ---------------- CSR build ----------------
__global__ void hist_k(const int* __restrict__ ei, int* __restrict__ counts) {
    int e = blockIdx.x * blockDim.x + threadIdx.x;
    if (e >= ET) return;
    int d = (e < EE) ? ei[EE + e] : e - EE;
    atomicAdd(&counts[d], 1);
}

__global__ void scan1_k(const int* __restrict__ counts, int* __restrict__ bsum) {
    __shared__ int sh[256];
    int t = threadIdx.x;
    int i = blockIdx.x * 256 + t;
    sh[t] = (i < NN) ? counts[i] : 0;
    __syncthreads();
    for (int off = 128; off > 0; off >>= 1) {
        if (t < off) sh[t] += sh[t + off];
        __syncthreads();
    }
    if (t == 0) bsum[blockIdx.x] = sh[0];
}

__global__ void scan2_k(int* __restrict__ bsum, int nb, int* __restrict__ start) {
    __shared__ int sh[256];
    int t = threadIdx.x;
    int v = (t < nb) ? bsum[t] : 0;
    sh[t] = v;
    __syncthreads();
    for (int off = 1; off < 256; off <<= 1) {
        int u = (t >= off) ? sh[t - off] : 0;
        __syncthreads();
        sh[t] += u;
        __syncthreads();
    }
    if (t < nb) bsum[t] = sh[t] - v;
    if (t == 0) start[NN] = ET;
}

__global__ void scan3_k(const int* __restrict__ counts, const int* __restrict__ bsum,
                        int* __restrict__ start, int* __restrict__ cursor) {
    __shared__ int sh[256];
    int t = threadIdx.x;
    int i = blockIdx.x * 256 + t;
    int c = (i < NN) ? counts[i] : 0;
    sh[t] = c;
    __syncthreads();
    for (int off = 1; off < 256; off <<= 1) {
        int u = (t >= off) ? sh[t - off] : 0;
        __syncthreads();
        sh[t] += u;
        __syncthreads();
    }
    int excl = sh[t] - c + bsum[blockIdx.x];
    if (i < NN) {
        start[i] = excl;
        cursor[i] = excl;
    }
}

__global__ void scatter_k(const int* __restrict__ ei, int* __restrict__ cursor,
                          int* __restrict__ csr) {
    int e = blockIdx.x * blockDim.x + threadIdx.x;
    if (e >= ET) return;
    int s, d;
    if (e < EE) { s = ei[e]; d = ei[EE + e]; } else { s = d = e - EE; }
    int slot = atomicAdd(&cursor[d], 1);
    csr[slot] = s;
}

// ---------------- fp32 -> bf16 convert (x) ----------------
__global__ void cvt_k(const float4* __restrict__ X, ushort4* __restrict__ Xb, int n4) {
    int i = blockIdx.x * blockDim.x + threadIdx.x;
    if (i >= n4) return;
    float4 v = X[i];
    ushort4 o;
    o.x = f2b(v.x);
    o.y = f2b(v.y);
    o.z = f2b(v.z);
    o.w = f2b(v.w);
    Xb[i] = o;
}

// ---------------- pack W into MFMA B-fragment layout ----------------
// Wp[((ctg*4 + ks)*64 + lane)*8 + j] = bf16(W[(ks*32 + (lane>>4)*8 + j)*OUT + ctg*16 + (lane&15)])
template <int OUT>
__global__ void packW_k(const float* __restrict__ W, unsigned short* __restrict__ Wp) {
    const int total = (OUT / 16) * 4 * 64;
    int id = blockIdx.x * 256 + threadIdx.x;
    if (id >= total) return;
    const int col = ((id >> 8) << 4) + (id & 15);
    const int k0 = ((id >> 6) & 3) * 32 + ((id >> 4) & 3) * 8;
    ushort4 lo, hi;
    lo.x = f2b(W[(k0 + 0) * OUT + col]);
    lo.y = f2b(W[(k0 + 1) * OUT + col]);
    lo.z = f2b(W[(k0 + 2) * OUT + col]);
    lo.w = f2b(W[(k0 + 3) * OUT + col]);
    hi.x = f2b(W[(k0 + 4) * OUT + col]);
    hi.y = f2b(W[(k0 + 5) * OUT + col]);
    hi.z = f2b(W[(k0 + 6) * OUT + col]);
    hi.w = f2b(W[(k0 + 7) * OUT + col]);
    ((ushort4*)Wp)[id * 2] = lo;
    ((ushort4*)Wp)[id * 2 + 1] = hi;
}

// ---------------- MFMA GEMM: H[M,OUT] = Xb[M,128] @ W, bf16 in/out, fp32 acc ------
// Block = 256 threads (4 waves), 64 rows; wave w covers cols [w*CT*16, (w+1)*CT*16).
template <int OUT, int CT>
__global__ void mfma_gemm_k(const unsigned short* __restrict__ Xb,
                            const unsigned short* __restrict__ Wp,
                            unsigned short* __restrict__ Hout) {
    const int wave = threadIdx.x >> 6;
    const int lane = threadIdx.x & 63;
    const int quad = lane >> 4;
    const int rl = lane & 15;
    const int r0 = blockIdx.x * 64;
    floatx4 acc[4][CT];
#pragma unroll
    for (int rt = 0; rt < 4; ++rt)
#pragma unroll
        for (int ct = 0; ct < CT; ++ct) acc[rt][ct] = {0.f, 0.f, 0.f, 0.f};

#pragma unroll
    for (int ks = 0; ks < 4; ++ks) {
        short8 a[4];
#pragma unroll
        for (int rt = 0; rt < 4; ++rt) {
            int row = r0 + rt * 16 + rl;
            row = row < NN ? row : NN - 1;
            a[rt] = *(const short8*)(Xb + (long long)row * 128 + ks * 32 + quad * 8);
        }
#pragma unroll
        for (int ct = 0; ct < CT; ++ct) {
            const int ctg = wave * CT + ct;
            const short8 b = *(const short8*)(Wp + (((ctg * 4 + ks) * 64 + lane) << 3));
#pragma unroll
            for (int rt = 0; rt < 4; ++rt)
                acc[rt][ct] = __builtin_amdgcn_mfma_f32_16x16x32_bf16(a[rt], b, acc[rt][ct], 0, 0, 0);
        }
    }
#pragma unroll
    for (int rt = 0; rt < 4; ++rt) {
        const int rowbase = r0 + rt * 16 + quad * 4;
#pragma unroll
        for (int ct = 0; ct < CT; ++ct) {
            const int col = (wave * CT + ct) * 16 + rl;
#pragma unroll
            for (int r = 0; r < 4; ++r) {
                const int row = rowbase + r;
                if (row < NN) Hout[(long long)row * OUT + col] = f2b(acc[rt][ct][r]);
            }
        }
    }
}

// ---------------- attention logit terms from h (bf16) ----------------
// als[n,hd] = sum_c h[n,hd*32+c]*a_src[hd,c]; one wave per row.
template <int OUT, int H>
__global__ void al_k(const unsigned short* __restrict__ Hb, const float* __restrict__ a_src,
                     const float* __restrict__ a_dst, float* __restrict__ als,
                     float* __restrict__ ald) {
    const int wave = threadIdx.x >> 6;
    const int lane = threadIdx.x & 63;
    const int row = blockIdx.x * 4 + wave;
    const int CPL = OUT / 64;       // cols per lane: 4 (OUT=256) or 2 (OUT=128)
    const int G = 32 / CPL;         // lanes per head group
    const int c0 = lane * CPL;
    const int hd = c0 >> 5;
    float ps = 0.f, pd = 0.f;
#pragma unroll
    for (int j = 0; j < CPL; ++j) {
        const float hv = b2f(Hb[(long long)row * OUT + c0 + j]);
        const int cc = hd * 32 + ((c0 + j) & 31);
        ps += hv * a_src[cc];
        pd += hv * a_dst[cc];
    }
#pragma unroll
    for (int m = G / 2; m >= 1; m >>= 1) {
        ps += __shfl_xor(ps, m, 64);
        pd += __shfl_xor(pd, m, 64);
    }
    if ((lane & (G - 1)) == 0) {
        als[row * H + hd] = ps;
        ald[row * H + hd] = pd;
    }
}

// ---------------- CSR gather: softmax-weighted aggregation + bias (+relu) ----------------
template <int OUT, int H, bool RELU>
__global__ void gather_k(const int* __restrict__ start, const int* __restrict__ csr,
                         const float* __restrict__ als, const float* __restrict__ ald,
                         const __hip_bfloat162* __restrict__ Hin,
                         const float* __restrict__ bias, __hip_bfloat162* __restrict__ outp) {
    const int d = blockIdx.x;
    const int t = threadIdx.x;      // owns channels 2t, 2t+1
    const int hd = t >> 4;          // (2t) >> 5
    const int beg = start[d];
    const int end = start[d + 1];
    const float aldd = ald[d * H + hd];
    float accx = 0.f, accy = 0.f, den = 0.f;
    int i = beg;
    for (; i + 4 <= end; i += 4) {
        const int s0 = csr[i], s1 = csr[i + 1], s2 = csr[i + 2], s3 = csr[i + 3];
        float l0 = als[s0 * H + hd] + aldd;
        float l1 = als[s1 * H + hd] + aldd;
        float l2 = als[s2 * H + hd] + aldd;
        float l3 = als[s3 * H + hd] + aldd;
        const __hip_bfloat162 g0 = Hin[(long long)s0 * (OUT / 2) + t];
        const __hip_bfloat162 g1 = Hin[(long long)s1 * (OUT / 2) + t];
        const __hip_bfloat162 g2 = Hin[(long long)s2 * (OUT / 2) + t];
        const __hip_bfloat162 g3 = Hin[(long long)s3 * (OUT / 2) + t];
        l0 = l0 > 0.f ? l0 : NEG_SLOPE * l0;
        l1 = l1 > 0.f ? l1 : NEG_SLOPE * l1;
        l2 = l2 > 0.f ? l2 : NEG_SLOPE * l2;
        l3 = l3 > 0.f ? l3 : NEG_SLOPE * l3;
        const float w0 = __expf(l0), w1 = __expf(l1), w2 = __expf(l2), w3 = __expf(l3);
        den += (w0 + w1) + (w2 + w3);
        const float2 f0 = __bfloat1622float2(g0);
        const float2 f1 = __bfloat1622float2(g1);
        const float2 f2 = __bfloat1622float2(g2);
        const float2 f3 = __bfloat1622float2(g3);
        accx += w0 * f0.x + w1 * f1.x + w2 * f2.x + w3 * f3.x;
        accy += w0 * f0.y + w1 * f1.y + w2 * f2.y + w3 * f3.y;
    }
    for (; i < end; ++i) {
        const int s = csr[i];
        float lg = als[s * H + hd] + aldd;
        lg = lg > 0.f ? lg : NEG_SLOPE * lg;
        const float w = __expf(lg);
        const float2 f = __bfloat1622float2(Hin[(long long)s * (OUT / 2) + t]);
        den += w;
        accx += w * f.x;
        accy += w * f.y;
    }
    const float inv = 1.f / (den + 1e-16f);
    float vx = accx * inv + bias[2 * t];
    float vy = accy * inv + bias[2 * t + 1];
    if (RELU) {
        vx = vx > 0.f ? vx : 0.f;
        vy = vy > 0.f ? vy : 0.f;
    }
    outp[(long long)d * (OUT / 2) + t] = pack_bf162(vx, vy);
}

// ---------------- decode: logits = sum(z2[a]*z2[b]), z2 in bf16 ----------------
__global__ void decode_k(const int* __restrict__ pei, const int* __restrict__ nei,
                         const __hip_bfloat162* __restrict__ z2, float* __restrict__ out) {
    const int w = threadIdx.x >> 6, lane = threadIdx.x & 63;
    const int idx = blockIdx.x * 4 + w;
    if (idx >= 2 * E_DEC) return;
    int a, b;
    if (idx < E_DEC) {
        a = pei[idx];
        b = pei[E_DEC + idx];
    } else {
        const int j = idx - E_DEC;
        a = nei[j];
        b = nei[E_DEC + j];
    }
    const __hip_bfloat162* za = z2 + (long long)a * 128;
    const __hip_bfloat162* zb = z2 + (long long)b * 128;
    float s = 0.f;
#pragma unroll
    for (int r = 0; r < 2; ++r) {
        const float2 fa = __bfloat1622float2(za[lane + 64 * r]);
        const float2 fb = __bfloat1622float2(zb[lane + 64 * r]);
        s += fa.x * fb.x + fa.y * fb.y;
    }
#pragma unroll
    for (int m = 32; m >= 1; m >>= 1) s += __shfl_xor(s, m, 64);
    if (lane == 0) out[idx] = s;
}

extern "C" void kernel_launch(void* const* d_in, const int* in_sizes, int n_in,
                              void* d_out, int out_size, void* d_ws, size_t ws_size,
                              hipStream_t stream) {
    const float* x = (const float*)d_in[0];
    const int* ei = (const int*)d_in[1];
    const int* pei = (const int*)d_in[2];
    const int* nei = (const int*)d_in[3];
    const float* W1 = (const float*)d_in[4];
    const float* as1 = (const float*)d_in[5];
    const float* ad1 = (const float*)d_in[6];
    const float* b1 = (const float*)d_in[7];
    const float* W2 = (const float*)d_in[8];
    const float* as2 = (const float*)d_in[9];
    const float* ad2 = (const float*)d_in[10];
    const float* b2 = (const float*)d_in[11];
    float* out = (float*)d_out;

    // ---- workspace layout: 16B-aligned bf16 region first, then fp32, then ints ----
    unsigned short* h1 = (unsigned short*)d_ws;              // NN*128
    unsigned short* h2 = h1 + (long long)NN * 128;           // NN*256
    unsigned short* z2 = h2 + (long long)NN * 256;           // NN*256
    unsigned short* z1 = z2 + (long long)NN * 256;           // NN*128
    unsigned short* xb = z1 + (long long)NN * 128;           // NN*128
    unsigned short* wp1 = xb + (long long)NN * 128;          // 128*128
    unsigned short* wp2 = wp1 + 128 * 128;                   // 128*256
    float* als1 = (float*)(wp2 + 128 * 256);                 // NN*H1
    float* ald1 = als1 + NN * H1;
    float* als2 = ald1 + NN * H1;                            // NN*H2
    float* ald2 = als2 + NN * H2;
    int* counts = (int*)(ald2 + NN * H2);                    // NN
    int* start = counts + NN;                                // NN+1
    int* cursor = start + NN + 1;                            // NN
    int* bsum = cursor + NN;                                 // 256
    int* csr = bsum + 256;                                   // ET

    const int NB = (NN + 255) / 256;  // 196

    // ---- CSR build ----
    fillint_k<<<NB, 256, 0, stream>>>(counts, NN);
    hist_k<<<(ET + 255) / 256, 256, 0, stream>>>(ei, counts);
    scan1_k<<<NB, 256, 0, stream>>>(counts, bsum);
    scan2_k<<<1, 256, 0, stream>>>(bsum, NB, start);
    scan3_k<<<NB, 256, 0, stream>>>(counts, bsum, start, cursor);
    scatter_k<<<(ET + 255) / 256, 256, 0, stream>>>(ei, cursor, csr);

    // ---- input conversion + weight packing ----
    const int n4 = NN * 128 / 4;
    cvt_k<<<(n4 + 255) / 256, 256, 0, stream>>>((const float4*)x, (ushort4*)xb, n4);
    packW_k<128><<<(2048 + 255) / 256, 256, 0, stream>>>(W1, wp1);
    packW_k<256><<<(4096 + 255) / 256, 256, 0, stream>>>(W2, wp2);

    // ---- conv1 ----
    mfma_gemm_k<128, 2><<<(NN + 63) / 64, 256, 0, stream>>>(xb, wp1, h1);
    al_k<128, H1><<<NN / 4, 256, 0, stream>>>(h1, as1, ad1, als1, ald1);
    gather_k<128, H1, true><<<NN, 64, 0, stream>>>(
        start, csr, als1, ald1, (const __hip_bfloat162*)h1, b1, (__hip_bfloat162*)z1);

    // ---- conv2 ----
    mfma_gemm_k<256, 4><<<(NN + 63) / 64, 256, 0, stream>>>(z1, wp2, h2);
    al_k<256, H2><<<NN / 4, 256, 0, stream>>>(h2, as2, ad2, als2, ald2);
    gather_k<256, H2, false><<<NN, 128, 0, stream>>>(
        start, csr, als2, ald2, (const __hip_bfloat162*)h2, b2, (__hip_bfloat162*)z2);

    // ---- decode ----
    decode_k<<<(2 * E_DEC + 3) / 4, 256, 0, stream>>>(
        pei, nei, (const __hip_bfloat162*)z2, out);
}